// Round 2
// baseline (327.663 us; speedup 1.0000x reference)
//
#include <hip/hip_runtime.h>
#include <math.h>

// Problem constants (fixed by reference setup_inputs):
//   x: (32,512,2049) fp32 -> out (32,512,1024) fp32
//   segments: n_lin (~631) linear, n_cub (~104) cubic, n_tri (~289) tri-max
#define NI 2049
#define ROWS 4            // rows per main block; 4*2049 floats start 16B-aligned
#define WCAP 4096         // cap on total packed tri weights (actual ~3.8K)
#define NTRI_MAX 512

// ---------------------------------------------------------------------------
// Pass 1: per tri row, find finite-weight window [start, start+cnt).
// ---------------------------------------------------------------------------
__global__ void logscale_win(const float* __restrict__ w, int n_in,
                             int* __restrict__ tri_start,
                             int* __restrict__ tri_cnt) {
    const int i = blockIdx.x;
    __shared__ int smin, smax;
    if (threadIdx.x == 0) { smin = n_in; smax = -1; }
    __syncthreads();
    int lmin = n_in, lmax = -1;
    const float* wr = w + (size_t)i * n_in;
    for (int b = threadIdx.x; b < n_in; b += blockDim.x) {
        float v = wr[b];
        if (v > -1e30f) { lmin = min(lmin, b); lmax = max(lmax, b); }
    }
    atomicMin(&smin, lmin);
    atomicMax(&smax, lmax);
    __syncthreads();
    if (threadIdx.x == 0) {
        int s = smin, cnt = smax - smin + 1;
        if (cnt < 1) { s = 0; cnt = 1; }
        if (cnt > 64) cnt = 64;          // defensive (real max ~28)
        tri_start[i] = s; tri_cnt[i] = cnt;
    }
}

// ---------------------------------------------------------------------------
// Pass 2 (single block): prefix-sum tri counts, build fused meta[n_out],
// compact-pack tri weights into wpk.
// meta layout per output o:
//   lin : x=i0(bits) y=i1(bits) z=f
//   cub : x=i0(bits)            z=f
//   tri : x=start(bits) y=cnt(bits) z=off(bits)
// ---------------------------------------------------------------------------
__global__ void logscale_pack(const float* __restrict__ w,
                              const float* __restrict__ flin,
                              const float* __restrict__ fcub,
                              const int*   __restrict__ pidx,
                              const int*   __restrict__ tri_start,
                              const int*   __restrict__ tri_cnt,
                              float4* __restrict__ meta,
                              float*  __restrict__ wpk,
                              int*    __restrict__ d_total,
                              int n_lin, int n_cub, int n_tri) {
    __shared__ int offs[NTRI_MAX + 1];
    __shared__ int starts[NTRI_MAX];
    const int tid = threadIdx.x;
    for (int i = tid; i < n_tri; i += blockDim.x) {
        offs[i + 1] = tri_cnt[i];
        starts[i]   = tri_start[i];
    }
    __syncthreads();
    if (tid == 0) {
        offs[0] = 0;
        for (int i = 1; i <= n_tri; ++i) offs[i] += offs[i - 1];
        int t = offs[n_tri]; if (t > WCAP) t = WCAP;
        *d_total = t;
    }
    __syncthreads();
    int total = offs[n_tri]; if (total > WCAP) total = WCAP;

    const int n_out = n_lin + n_cub + n_tri;
    for (int o = tid; o < n_out; o += blockDim.x) {
        float4 m;
        if (o < n_lin) {
            m.x = __int_as_float(pidx[o]);
            m.y = __int_as_float(pidx[n_lin + o]);
            m.z = flin[o]; m.w = 0.0f;
        } else if (o < n_lin + n_cub) {
            float c = fcub[o - n_lin];
            int i0 = (int)floorf(c);
            m.x = __int_as_float(i0);
            m.y = 0.0f;
            m.z = c - (float)i0; m.w = 0.0f;
        } else {
            int i = o - n_lin - n_cub;
            int oa = min(offs[i], WCAP), ob = min(offs[i + 1], WCAP);
            m.x = __int_as_float(starts[i]);
            m.y = __int_as_float(ob - oa);
            m.z = __int_as_float(oa); m.w = 0.0f;
        }
        meta[o] = m;
    }
    // pack weights: flat index -> (row, j) via binary search on offs
    for (int p = tid; p < total; p += blockDim.x) {
        int lo = 0, hi = n_tri - 1;
        while (lo < hi) {
            int mid = (lo + hi + 1) >> 1;
            if (offs[mid] <= p) lo = mid; else hi = mid - 1;
        }
        int j = p - offs[lo];
        wpk[p] = w[(size_t)lo * NI + starts[lo] + j];
    }
}

// ---------------------------------------------------------------------------
// Main: ROWS rows per block. x staged via float4 (chunk is 16B-aligned and
// exactly ROWS*NI/4 float4s). Packed tri weights staged in LDS. One float4
// meta read per output.
// ---------------------------------------------------------------------------
__global__ __launch_bounds__(256) void logscale_main(
    const float*  __restrict__ x,
    const float4* __restrict__ meta,
    const float*  __restrict__ wpk,
    const int*    __restrict__ d_total,
    float* __restrict__ out,
    int n_lin, int n_cub, int n_out, int n_rows) {

    __shared__ float xs[ROWS * NI];   // 8196 floats = 32784 B
    __shared__ float wl[WCAP];        // 16384 B

    const int tid  = threadIdx.x;
    const int row0 = blockIdx.x * ROWS;
    const int rows_here = min(ROWS, n_rows - row0);

    if (rows_here == ROWS) {
        const float4* xc = (const float4*)(x + (size_t)row0 * NI);
        for (int i = tid; i < (ROWS * NI) / 4; i += 256)
            ((float4*)xs)[i] = xc[i];
        if ((ROWS * NI) & 3) { /* not taken: 8196 % 4 == 0 */ }
    } else {
        const float* xr = x + (size_t)row0 * NI;
        for (int i = tid; i < rows_here * NI; i += 256) xs[i] = xr[i];
    }
    const int tw = *d_total;
    for (int i = tid; i < tw; i += 256) wl[i] = wpk[i];
    __syncthreads();

    const int n_lc = n_lin + n_cub;
    float* ob = out + (size_t)row0 * n_out;
    for (int r = 0; r < rows_here; ++r) {
        const float* xrow = xs + r * NI;
        for (int o = tid; o < n_out; o += 256) {
            float4 m = meta[o];
            float res;
            if (o < n_lin) {
                const int i0 = __float_as_int(m.x);
                const int i1 = __float_as_int(m.y);
                const float f = m.z;
                const float x0 = xrow[i0];
                const float x1 = xrow[i1];
                res = x0 + f * (x1 - x0);
            } else if (o < n_lc) {
                const int i0 = __float_as_int(m.x);
                const float f = m.z;
                const float xm1 = xrow[i0 - 1];
                const float x0  = xrow[i0];
                const float x1  = xrow[i0 + 1];
                const float x2  = xrow[i0 + 2];
                res = x0 + 0.5f * f * (x1 - xm1 +
                        f * (2.0f * xm1 - 5.0f * x0 + 4.0f * x1 - x2 +
                        f * (3.0f * (x0 - x1) + x2 - xm1)));
            } else {
                const int s   = __float_as_int(m.x);
                const int cnt = __float_as_int(m.y);
                const int off = __float_as_int(m.z);
                float mx = -INFINITY;
                #pragma unroll 4
                for (int j = 0; j < cnt; ++j)
                    mx = fmaxf(mx, xrow[s + j] + wl[off + j]);
                res = mx;
            }
            ob[(size_t)r * n_out + o] = res;
        }
    }
}

extern "C" void kernel_launch(void* const* d_in, const int* in_sizes, int n_in,
                              void* d_out, int out_size, void* d_ws, size_t ws_size,
                              hipStream_t stream) {
    (void)n_in; (void)ws_size; (void)out_size;
    const float* x    = (const float*)d_in[0];
    const float* flin = (const float*)d_in[1];
    const float* fcub = (const float*)d_in[2];
    const float* w    = (const float*)d_in[3];
    const int*   pidx = (const int*)d_in[4];
    float* out = (float*)d_out;

    const int n_lin  = in_sizes[1];
    const int n_cub  = in_sizes[2];
    const int n_tri  = in_sizes[3] / NI;
    const int n_rows = in_sizes[0] / NI;
    const int n_out  = n_lin + n_cub + n_tri;

    // ws layout (16B-aligned first): meta[n_out] | wpk[WCAP] | start | cnt | total
    float4* meta      = (float4*)d_ws;
    float*  wpk       = (float*)(meta + n_out);
    int*    tri_start = (int*)(wpk + WCAP);
    int*    tri_cnt   = tri_start + NTRI_MAX;
    int*    d_total   = tri_cnt + NTRI_MAX;

    if (n_tri > 0)
        logscale_win<<<n_tri, 256, 0, stream>>>(w, NI, tri_start, tri_cnt);
    logscale_pack<<<1, 256, 0, stream>>>(w, flin, fcub, pidx, tri_start, tri_cnt,
                                         meta, wpk, d_total, n_lin, n_cub, n_tri);
    const int nblk = (n_rows + ROWS - 1) / ROWS;
    logscale_main<<<nblk, 256, 0, stream>>>(x, meta, wpk, d_total, out,
                                            n_lin, n_cub, n_out, n_rows);
}

// Round 3
// 272.022 us; speedup vs baseline: 1.2045x; 1.2045x over previous
//
#include <hip/hip_runtime.h>
#include <math.h>

// x: (32,512,2049) fp32 -> out (32,512,1024) fp32
// segments: n_lin (~631) linear, n_cub (~104) cubic, n_tri (~289) tri-max
#define NI 2049
#define ROWS 4
#define WCAP 4096
#define NTRI_MAX 512

// LDS pad-swizzle: +1 float per 32 -> stride-32 gathers become conflict-free
__device__ __forceinline__ int pad(int i) { return i + (i >> 5); }
#define XS_SZ (ROWS * NI + (ROWS * NI >> 5) + 4)   // 8452
#define WL_SZ (WCAP + (WCAP >> 5) + 4)             // 4228

// ---------------------------------------------------------------------------
// Pass 1: per tri row, find finite-weight window [start, start+cnt).
// ---------------------------------------------------------------------------
__global__ void logscale_win(const float* __restrict__ w, int n_in,
                             int* __restrict__ tri_start,
                             int* __restrict__ tri_cnt) {
    const int i = blockIdx.x;
    __shared__ int smin, smax;
    if (threadIdx.x == 0) { smin = n_in; smax = -1; }
    __syncthreads();
    int lmin = n_in, lmax = -1;
    const float* wr = w + (size_t)i * n_in;
    for (int b = threadIdx.x; b < n_in; b += blockDim.x) {
        float v = wr[b];
        if (v > -1e30f) { lmin = min(lmin, b); lmax = max(lmax, b); }
    }
    atomicMin(&smin, lmin);
    atomicMax(&smax, lmax);
    __syncthreads();
    if (threadIdx.x == 0) {
        int s = smin, cnt = smax - smin + 1;
        if (cnt < 1) { s = 0; cnt = 1; }
        if (cnt > 64) cnt = 64;          // defensive (real max ~28)
        tri_start[i] = s; tri_cnt[i] = cnt;
    }
}

// ---------------------------------------------------------------------------
// Pass 2 (single block): prefix-sum tri counts, build fused meta[n_out],
// compact-pack tri weights.
// meta per output o:
//   lin : x=i0 y=i1 z=f
//   cub : x=i0      z=f
//   tri : x=start y=cnt z=off
// ---------------------------------------------------------------------------
__global__ void logscale_pack(const float* __restrict__ w,
                              const float* __restrict__ flin,
                              const float* __restrict__ fcub,
                              const int*   __restrict__ pidx,
                              const int*   __restrict__ tri_start,
                              const int*   __restrict__ tri_cnt,
                              float4* __restrict__ meta,
                              float*  __restrict__ wpk,
                              int*    __restrict__ d_total,
                              int n_lin, int n_cub, int n_tri) {
    __shared__ int offs[NTRI_MAX + 1];
    __shared__ int starts[NTRI_MAX];
    const int tid = threadIdx.x;
    for (int i = tid; i < n_tri; i += blockDim.x) {
        offs[i + 1] = tri_cnt[i];
        starts[i]   = tri_start[i];
    }
    __syncthreads();
    if (tid == 0) {
        offs[0] = 0;
        for (int i = 1; i <= n_tri; ++i) offs[i] += offs[i - 1];
        int t = offs[n_tri]; if (t > WCAP) t = WCAP;
        *d_total = t;
    }
    __syncthreads();
    int total = offs[n_tri]; if (total > WCAP) total = WCAP;

    const int n_out = n_lin + n_cub + n_tri;
    for (int o = tid; o < n_out; o += blockDim.x) {
        float4 m;
        if (o < n_lin) {
            m.x = __int_as_float(pidx[o]);
            m.y = __int_as_float(pidx[n_lin + o]);
            m.z = flin[o]; m.w = 0.0f;
        } else if (o < n_lin + n_cub) {
            float c = fcub[o - n_lin];
            int i0 = (int)floorf(c);
            m.x = __int_as_float(i0);
            m.y = 0.0f;
            m.z = c - (float)i0; m.w = 0.0f;
        } else {
            int i = o - n_lin - n_cub;
            int oa = min(offs[i], WCAP), ob = min(offs[i + 1], WCAP);
            m.x = __int_as_float(starts[i]);
            m.y = __int_as_float(ob - oa);
            m.z = __int_as_float(oa); m.w = 0.0f;
        }
        meta[o] = m;
    }
    for (int p = tid; p < total; p += blockDim.x) {
        int lo = 0, hi = n_tri - 1;
        while (lo < hi) {
            int mid = (lo + hi + 1) >> 1;
            if (offs[mid] <= p) lo = mid; else hi = mid - 1;
        }
        int j = p - offs[lo];
        wpk[p] = w[(size_t)lo * NI + starts[lo] + j];
    }
}

// ---------------------------------------------------------------------------
// Main: ROWS rows per block, pad-swizzled LDS, outer loop over outputs with
// the row loop inside (meta + tri weights read once per ROWS rows).
// ---------------------------------------------------------------------------
__global__ __launch_bounds__(256) void logscale_main(
    const float*  __restrict__ x,
    const float4* __restrict__ meta,
    const float*  __restrict__ wpk,
    const int*    __restrict__ d_total,
    float* __restrict__ out,
    int n_lin, int n_cub, int n_out, int n_rows) {

    __shared__ float xs[XS_SZ];
    __shared__ float wl[WL_SZ];

    const int tid  = threadIdx.x;
    const int row0 = blockIdx.x * ROWS;
    const int rows_here = min(ROWS, n_rows - row0);

    // stride-1 scalar staging: coalesced global dword loads, conflict-free
    // padded LDS writes (consecutive lanes -> consecutive banks).
    const float* xr = x + (size_t)row0 * NI;
    const int nx = rows_here * NI;
    for (int i = tid; i < nx; i += 256) xs[pad(i)] = xr[i];
    const int tw = *d_total;
    for (int i = tid; i < tw; i += 256) wl[pad(i)] = wpk[i];
    __syncthreads();

    const int n_lc = n_lin + n_cub;
    float* ob = out + (size_t)row0 * n_out;

    if (rows_here == ROWS) {
        for (int o = tid; o < n_out; o += 256) {
            const float4 m = meta[o];
            float res[ROWS];
            if (o < n_lin) {
                const int i0 = __float_as_int(m.x);
                const int i1 = __float_as_int(m.y);
                const float f = m.z;
                #pragma unroll
                for (int r = 0; r < ROWS; ++r) {
                    const int b = r * NI;
                    const float x0 = xs[pad(b + i0)];
                    const float x1 = xs[pad(b + i1)];
                    res[r] = x0 + f * (x1 - x0);
                }
            } else if (o < n_lc) {
                const int i0 = __float_as_int(m.x);
                const float f = m.z;
                #pragma unroll
                for (int r = 0; r < ROWS; ++r) {
                    const int b = r * NI + i0;
                    const float xm1 = xs[pad(b - 1)];
                    const float x0  = xs[pad(b)];
                    const float x1  = xs[pad(b + 1)];
                    const float x2  = xs[pad(b + 2)];
                    res[r] = x0 + 0.5f * f * (x1 - xm1 +
                             f * (2.0f * xm1 - 5.0f * x0 + 4.0f * x1 - x2 +
                             f * (3.0f * (x0 - x1) + x2 - xm1)));
                }
            } else {
                const int s   = __float_as_int(m.x);
                const int cnt = __float_as_int(m.y);
                const int off = __float_as_int(m.z);
                float acc0 = -INFINITY, acc1 = -INFINITY;
                float acc2 = -INFINITY, acc3 = -INFINITY;
                for (int j = 0; j < cnt; ++j) {
                    const float wj = wl[pad(off + j)];
                    const int b = s + j;
                    acc0 = fmaxf(acc0, xs[pad(b)] + wj);
                    acc1 = fmaxf(acc1, xs[pad(b + NI)] + wj);
                    acc2 = fmaxf(acc2, xs[pad(b + 2 * NI)] + wj);
                    acc3 = fmaxf(acc3, xs[pad(b + 3 * NI)] + wj);
                }
                res[0] = acc0; res[1] = acc1; res[2] = acc2; res[3] = acc3;
            }
            #pragma unroll
            for (int r = 0; r < ROWS; ++r)
                ob[(size_t)r * n_out + o] = res[r];
        }
    } else {
        for (int o = tid; o < n_out; o += 256) {
            const float4 m = meta[o];
            for (int r = 0; r < rows_here; ++r) {
                const int b = r * NI;
                float res;
                if (o < n_lin) {
                    const int i0 = __float_as_int(m.x);
                    const int i1 = __float_as_int(m.y);
                    const float f = m.z;
                    const float x0 = xs[pad(b + i0)];
                    const float x1 = xs[pad(b + i1)];
                    res = x0 + f * (x1 - x0);
                } else if (o < n_lc) {
                    const int i0 = __float_as_int(m.x) + b;
                    const float f = m.z;
                    const float xm1 = xs[pad(i0 - 1)];
                    const float x0  = xs[pad(i0)];
                    const float x1  = xs[pad(i0 + 1)];
                    const float x2  = xs[pad(i0 + 2)];
                    res = x0 + 0.5f * f * (x1 - xm1 +
                          f * (2.0f * xm1 - 5.0f * x0 + 4.0f * x1 - x2 +
                          f * (3.0f * (x0 - x1) + x2 - xm1)));
                } else {
                    const int s   = __float_as_int(m.x) + b;
                    const int cnt = __float_as_int(m.y);
                    const int off = __float_as_int(m.z);
                    float mx = -INFINITY;
                    for (int j = 0; j < cnt; ++j)
                        mx = fmaxf(mx, xs[pad(s + j)] + wl[pad(off + j)]);
                    res = mx;
                }
                ob[(size_t)r * n_out + o] = res;
            }
        }
    }
}

extern "C" void kernel_launch(void* const* d_in, const int* in_sizes, int n_in,
                              void* d_out, int out_size, void* d_ws, size_t ws_size,
                              hipStream_t stream) {
    (void)n_in; (void)ws_size; (void)out_size;
    const float* x    = (const float*)d_in[0];
    const float* flin = (const float*)d_in[1];
    const float* fcub = (const float*)d_in[2];
    const float* w    = (const float*)d_in[3];
    const int*   pidx = (const int*)d_in[4];
    float* out = (float*)d_out;

    const int n_lin  = in_sizes[1];
    const int n_cub  = in_sizes[2];
    const int n_tri  = in_sizes[3] / NI;
    const int n_rows = in_sizes[0] / NI;
    const int n_out  = n_lin + n_cub + n_tri;

    // ws layout: meta[n_out] | wpk[WCAP] | tri_start | tri_cnt | total
    float4* meta      = (float4*)d_ws;
    float*  wpk       = (float*)(meta + n_out);
    int*    tri_start = (int*)(wpk + WCAP);
    int*    tri_cnt   = tri_start + NTRI_MAX;
    int*    d_total   = tri_cnt + NTRI_MAX;

    if (n_tri > 0)
        logscale_win<<<n_tri, 256, 0, stream>>>(w, NI, tri_start, tri_cnt);
    logscale_pack<<<1, 256, 0, stream>>>(w, flin, fcub, pidx, tri_start, tri_cnt,
                                         meta, wpk, d_total, n_lin, n_cub, n_tri);
    const int nblk = (n_rows + ROWS - 1) / ROWS;
    logscale_main<<<nblk, 256, 0, stream>>>(x, meta, wpk, d_total, out,
                                            n_lin, n_cub, n_out, n_rows);
}